// Round 1
// baseline (145.319 us; speedup 1.0000x reference)
//
#include <hip/hip_runtime.h>

// RoiAlign (tf.image.crop_and_resize semantics, bilinear, extrapolation=0)
// Shapes fixed by the problem: fm [8,64,64,256] f32, boxes [8,1000,4] f32,
// P=7. Output [8,1000,7,7,256] f32 (~401 MB) -> write-bound kernel.
//
// Mapping: 1 wave (64 lanes) per output position (b,n,py,px).
// Lane i covers channels [4i,4i+4) via float4: 64*16B = 1KB coalesced.

#define BATCH 8
#define FH 64
#define FW 64
#define FC 256
#define NBOX 1000
#define PP 7

__global__ __launch_bounds__(256) void roi_align_kernel(
    const float* __restrict__ fm,
    const float* __restrict__ boxes,
    float* __restrict__ out,
    int n_pos)
{
    const int gtid = blockIdx.x * blockDim.x + threadIdx.x;
    const int pos  = gtid >> 6;          // one wave per output position
    const int lane = threadIdx.x & 63;
    if (pos >= n_pos) return;

    // pos = ((b*NBOX + n)*PP + py)*PP + px
    const int pp = pos % (PP * PP);
    const int bn = pos / (PP * PP);      // b*NBOX + n
    const int py = pp / PP;
    const int px = pp % PP;
    const int b  = bn / NBOX;

    // Box: [y1,x1,y2,x2] normalized
    const float* bx = boxes + bn * 4;
    const float y1 = bx[0];
    const float x1 = bx[1];
    const float y2 = bx[2];
    const float x2 = bx[3];

    // Reference: ys = y1*(h-1) + t*((y2-y1)*(h-1)/(P-1))
    const float yc = y1 * (float)(FH - 1)
                   + (float)py * ((y2 - y1) * (float)(FH - 1) / (float)(PP - 1));
    const float xc = x1 * (float)(FW - 1)
                   + (float)px * ((x2 - x1) * (float)(FW - 1) / (float)(PP - 1));

    // lin(): lo=floor, frac=coords-lo, clip indices, validity
    const float ylo_f = floorf(yc);
    const float wy    = yc - ylo_f;
    int y_lo = (int)ylo_f;               // safe: |yc| < 2^30 here
    int y_hi = y_lo + 1;
    y_lo = min(max(y_lo, 0), FH - 1);
    y_hi = min(max(y_hi, 0), FH - 1);
    const bool vy = (yc >= 0.0f) && (yc <= (float)(FH - 1));

    const float xlo_f = floorf(xc);
    const float wx    = xc - xlo_f;
    int x_lo = (int)xlo_f;
    int x_hi = x_lo + 1;
    x_lo = min(max(x_lo, 0), FW - 1);
    x_hi = min(max(x_hi, 0), FW - 1);
    const bool vx = (xc >= 0.0f) && (xc <= (float)(FW - 1));

    const bool valid = vy && vx;

    const int c4 = lane * 4;             // channel offset for this lane

    // fm[b, y, x, c] at ((b*FH + y)*FW + x)*FC + c
    const int rowb = b * FH;
    const float* p00 = fm + (size_t)(((rowb + y_lo) * FW) + x_lo) * FC + c4;
    const float* p01 = fm + (size_t)(((rowb + y_lo) * FW) + x_hi) * FC + c4;
    const float* p10 = fm + (size_t)(((rowb + y_hi) * FW) + x_lo) * FC + c4;
    const float* p11 = fm + (size_t)(((rowb + y_hi) * FW) + x_hi) * FC + c4;

    float4 r;
    if (valid) {
        const float4 v00 = *(const float4*)p00;
        const float4 v01 = *(const float4*)p01;
        const float4 v10 = *(const float4*)p10;
        const float4 v11 = *(const float4*)p11;

        // top = v00 + (v01-v00)*wx; bot = v10 + (v11-v10)*wx;
        // out = top + (bot-top)*wy   (exact reference formula order)
        float4 top, bot;
        top.x = v00.x + (v01.x - v00.x) * wx;
        top.y = v00.y + (v01.y - v00.y) * wx;
        top.z = v00.z + (v01.z - v00.z) * wx;
        top.w = v00.w + (v01.w - v00.w) * wx;
        bot.x = v10.x + (v11.x - v10.x) * wx;
        bot.y = v10.y + (v11.y - v10.y) * wx;
        bot.z = v10.z + (v11.z - v10.z) * wx;
        bot.w = v10.w + (v11.w - v10.w) * wx;
        r.x = top.x + (bot.x - top.x) * wy;
        r.y = top.y + (bot.y - top.y) * wy;
        r.z = top.z + (bot.z - top.z) * wy;
        r.w = top.w + (bot.w - top.w) * wy;
    } else {
        r.x = 0.0f; r.y = 0.0f; r.z = 0.0f; r.w = 0.0f;
    }

    float* po = out + (size_t)pos * FC + c4;
    *(float4*)po = r;
}

extern "C" void kernel_launch(void* const* d_in, const int* in_sizes, int n_in,
                              void* d_out, int out_size, void* d_ws, size_t ws_size,
                              hipStream_t stream) {
    const float* fm    = (const float*)d_in[0];
    const float* boxes = (const float*)d_in[1];
    float* out = (float*)d_out;

    const int n_pos = BATCH * NBOX * PP * PP;   // 392000 waves
    const int threads = 256;                    // 4 waves/block
    const int blocks = (n_pos * 64 + threads - 1) / threads;  // 98000

    roi_align_kernel<<<blocks, threads, 0, stream>>>(fm, boxes, out, n_pos);
}

// Round 2
// 134.443 us; speedup vs baseline: 1.0809x; 1.0809x over previous
//
#include <hip/hip_runtime.h>

// RoiAlign (tf.image.crop_and_resize, bilinear, extrapolation=0)
// fm [8,64,64,256] f32, boxes [8,1000,4] f32, P=7 -> out [8,1000,7,7,256] f32.
//
// Mapping: 1 wave per output position (b,n,py,px); lane i -> channels [4i,4i+4)
// as float4 (64 lanes * 16B = 1KB coalesced per tap load / store).
//
// XCD-batch partitioning: b = blockIdx.x % 8. Blocks round-robin across the 8
// XCDs, so each XCD processes exactly one batch; that batch's fm slice is
// 64*64*256*4B = 4MB = one XCD's L2. Tap reads then hit L2 instead of L3/HBM.

#define BATCH 8
#define FH 64
#define FW 64
#define FC 256
#define NBOX 1000
#define PP 7
#define POS_PER_BATCH (NBOX * PP * PP)   // 49000

__global__ __launch_bounds__(256) void roi_align_kernel(
    const float* __restrict__ fm,
    const float* __restrict__ boxes,
    float* __restrict__ out)
{
    const int lane = threadIdx.x & 63;
    const int wib  = threadIdx.x >> 6;          // wave in block: 0..3

    const int b    = blockIdx.x & 7;            // batch == XCD (round-robin)
    const int lblk = blockIdx.x >> 3;           // 0..12249
    const int lpos = lblk * 4 + wib;            // 0..48999 within batch
    if (lpos >= POS_PER_BATCH) return;

    // lpos = (n*PP + py)*PP + px
    const int pp = lpos % (PP * PP);
    const int n  = lpos / (PP * PP);
    const int py = pp / PP;
    const int px = pp % PP;
    const int bn = b * NBOX + n;

    // Box: [y1,x1,y2,x2] normalized (wave-uniform -> scalar loads)
    const float* bx = boxes + bn * 4;
    const float y1 = bx[0];
    const float x1 = bx[1];
    const float y2 = bx[2];
    const float x2 = bx[3];

    // Reference: ys = y1*(h-1) + t*((y2-y1)*(h-1)/(P-1))  (exact formula order)
    const float yc = y1 * (float)(FH - 1)
                   + (float)py * ((y2 - y1) * (float)(FH - 1) / (float)(PP - 1));
    const float xc = x1 * (float)(FW - 1)
                   + (float)px * ((x2 - x1) * (float)(FW - 1) / (float)(PP - 1));

    // lin(): lo=floor, frac=coords-lo, clip indices, validity
    const float ylo_f = floorf(yc);
    const float wy    = yc - ylo_f;
    int y_lo = (int)ylo_f;
    int y_hi = y_lo + 1;
    y_lo = min(max(y_lo, 0), FH - 1);
    y_hi = min(max(y_hi, 0), FH - 1);
    const bool vy = (yc >= 0.0f) && (yc <= (float)(FH - 1));

    const float xlo_f = floorf(xc);
    const float wx    = xc - xlo_f;
    int x_lo = (int)xlo_f;
    int x_hi = x_lo + 1;
    x_lo = min(max(x_lo, 0), FW - 1);
    x_hi = min(max(x_hi, 0), FW - 1);
    const bool vx = (xc >= 0.0f) && (xc <= (float)(FW - 1));

    const float vmask = (vy && vx) ? 1.0f : 0.0f;

    const int c4 = lane * 4;                    // channel offset for this lane

    // fm[b, y, x, c] at ((b*FH + y)*FW + x)*FC + c. Indices are clamped ->
    // loads are always safe; issue unconditionally (no branch), mask at end.
    const int rowb = b * FH;
    const float4 v00 = *(const float4*)(fm + (size_t)(((rowb + y_lo) * FW) + x_lo) * FC + c4);
    const float4 v01 = *(const float4*)(fm + (size_t)(((rowb + y_lo) * FW) + x_hi) * FC + c4);
    const float4 v10 = *(const float4*)(fm + (size_t)(((rowb + y_hi) * FW) + x_lo) * FC + c4);
    const float4 v11 = *(const float4*)(fm + (size_t)(((rowb + y_hi) * FW) + x_hi) * FC + c4);

    // top = v00 + (v01-v00)*wx; bot = v10 + (v11-v10)*wx;
    // out = top + (bot-top)*wy   (exact reference order), then zero if invalid
    float4 top, bot, r;
    top.x = v00.x + (v01.x - v00.x) * wx;
    top.y = v00.y + (v01.y - v00.y) * wx;
    top.z = v00.z + (v01.z - v00.z) * wx;
    top.w = v00.w + (v01.w - v00.w) * wx;
    bot.x = v10.x + (v11.x - v10.x) * wx;
    bot.y = v10.y + (v11.y - v10.y) * wx;
    bot.z = v10.z + (v11.z - v10.z) * wx;
    bot.w = v10.w + (v11.w - v10.w) * wx;
    r.x = (top.x + (bot.x - top.x) * wy) * vmask;
    r.y = (top.y + (bot.y - top.y) * wy) * vmask;
    r.z = (top.z + (bot.z - top.z) * wy) * vmask;
    r.w = (top.w + (bot.w - top.w) * wy) * vmask;

    const size_t pos = (size_t)b * POS_PER_BATCH + lpos;
    float* po = out + pos * FC + c4;
    *(float4*)po = r;
}

extern "C" void kernel_launch(void* const* d_in, const int* in_sizes, int n_in,
                              void* d_out, int out_size, void* d_ws, size_t ws_size,
                              hipStream_t stream) {
    const float* fm    = (const float*)d_in[0];
    const float* boxes = (const float*)d_in[1];
    float* out = (float*)d_out;

    const int threads = 256;                         // 4 waves/block
    const int blocks  = BATCH * (POS_PER_BATCH / 4); // 8 * 12250 = 98000

    roi_align_kernel<<<blocks, threads, 0, stream>>>(fm, boxes, out);
}

// Round 3
// 96.649 us; speedup vs baseline: 1.5036x; 1.3910x over previous
//
#include <hip/hip_runtime.h>

// RoiAlign (tf.image.crop_and_resize, bilinear, extrapolation=0)
// fm [8,64,64,256] f32, boxes [8,1000,4] f32, P=7 -> out [8,1000,7,7,256] f32.
//
// Mapping: 1 wave per output position (b,n,py,px); lane i -> channels [4i,4i+4)
// as float4 (64 lanes * 16B = 1KB coalesced per tap load / store).
//
// XCD-batch partitioning: b = blockIdx.x % 8 -> each XCD serves one batch;
// that batch's fm slice (4MB) == one XCD L2.
//
// Non-temporal output stores: the 401MB write stream must NOT write-allocate
// in L2, or it evicts the 4MB fm working set and tap reads fall to L3/HBM.
// __builtin_nontemporal_store -> global_store_dwordx4 ... nt.

#define BATCH 8
#define FH 64
#define FW 64
#define FC 256
#define NBOX 1000
#define PP 7
#define POS_PER_BATCH (NBOX * PP * PP)   // 49000

typedef __attribute__((ext_vector_type(4))) float f32x4;

__global__ __launch_bounds__(256) void roi_align_kernel(
    const float* __restrict__ fm,
    const float* __restrict__ boxes,
    float* __restrict__ out)
{
    const int lane = threadIdx.x & 63;
    const int wib  = threadIdx.x >> 6;          // wave in block: 0..3

    const int b    = blockIdx.x & 7;            // batch == XCD (round-robin)
    const int lblk = blockIdx.x >> 3;           // 0..12249
    const int lpos = lblk * 4 + wib;            // 0..48999 within batch
    if (lpos >= POS_PER_BATCH) return;

    // lpos = (n*PP + py)*PP + px
    const int pp = lpos % (PP * PP);
    const int n  = lpos / (PP * PP);
    const int py = pp / PP;
    const int px = pp % PP;
    const int bn = b * NBOX + n;

    // Box: [y1,x1,y2,x2] normalized (wave-uniform -> scalar loads)
    const float* bx = boxes + bn * 4;
    const float y1 = bx[0];
    const float x1 = bx[1];
    const float y2 = bx[2];
    const float x2 = bx[3];

    // Reference: ys = y1*(h-1) + t*((y2-y1)*(h-1)/(P-1))  (exact formula order)
    const float yc = y1 * (float)(FH - 1)
                   + (float)py * ((y2 - y1) * (float)(FH - 1) / (float)(PP - 1));
    const float xc = x1 * (float)(FW - 1)
                   + (float)px * ((x2 - x1) * (float)(FW - 1) / (float)(PP - 1));

    // lin(): lo=floor, frac=coords-lo, clip indices, validity
    const float ylo_f = floorf(yc);
    const float wy    = yc - ylo_f;
    int y_lo = (int)ylo_f;
    int y_hi = y_lo + 1;
    y_lo = min(max(y_lo, 0), FH - 1);
    y_hi = min(max(y_hi, 0), FH - 1);
    const bool vy = (yc >= 0.0f) && (yc <= (float)(FH - 1));

    const float xlo_f = floorf(xc);
    const float wx    = xc - xlo_f;
    int x_lo = (int)xlo_f;
    int x_hi = x_lo + 1;
    x_lo = min(max(x_lo, 0), FW - 1);
    x_hi = min(max(x_hi, 0), FW - 1);
    const bool vx = (xc >= 0.0f) && (xc <= (float)(FW - 1));

    const float vmask = (vy && vx) ? 1.0f : 0.0f;

    const int c4 = lane * 4;                    // channel offset for this lane

    // fm[b, y, x, c] at ((b*FH + y)*FW + x)*FC + c. Indices clamped -> safe;
    // issue unconditionally, mask at end.
    const int rowb = b * FH;
    const float4 v00 = *(const float4*)(fm + (size_t)(((rowb + y_lo) * FW) + x_lo) * FC + c4);
    const float4 v01 = *(const float4*)(fm + (size_t)(((rowb + y_lo) * FW) + x_hi) * FC + c4);
    const float4 v10 = *(const float4*)(fm + (size_t)(((rowb + y_hi) * FW) + x_lo) * FC + c4);
    const float4 v11 = *(const float4*)(fm + (size_t)(((rowb + y_hi) * FW) + x_hi) * FC + c4);

    // top = v00 + (v01-v00)*wx; bot = v10 + (v11-v10)*wx;
    // out = top + (bot-top)*wy   (exact reference order), then zero if invalid
    float4 top, bot;
    f32x4 r;
    top.x = v00.x + (v01.x - v00.x) * wx;
    top.y = v00.y + (v01.y - v00.y) * wx;
    top.z = v00.z + (v01.z - v00.z) * wx;
    top.w = v00.w + (v01.w - v00.w) * wx;
    bot.x = v10.x + (v11.x - v10.x) * wx;
    bot.y = v10.y + (v11.y - v10.y) * wx;
    bot.z = v10.z + (v11.z - v10.z) * wx;
    bot.w = v10.w + (v11.w - v10.w) * wx;
    r.x = (top.x + (bot.x - top.x) * wy) * vmask;
    r.y = (top.y + (bot.y - top.y) * wy) * vmask;
    r.z = (top.z + (bot.z - top.z) * wy) * vmask;
    r.w = (top.w + (bot.w - top.w) * wy) * vmask;

    const size_t pos = (size_t)b * POS_PER_BATCH + lpos;
    float* po = out + pos * FC + c4;
    __builtin_nontemporal_store(r, (f32x4*)po);   // nt: bypass L2 allocation
}

extern "C" void kernel_launch(void* const* d_in, const int* in_sizes, int n_in,
                              void* d_out, int out_size, void* d_ws, size_t ws_size,
                              hipStream_t stream) {
    const float* fm    = (const float*)d_in[0];
    const float* boxes = (const float*)d_in[1];
    float* out = (float*)d_out;

    const int threads = 256;                         // 4 waves/block
    const int blocks  = BATCH * (POS_PER_BATCH / 4); // 8 * 12250 = 98000

    roi_align_kernel<<<blocks, threads, 0, stream>>>(fm, boxes, out);
}

// Round 4
// 94.419 us; speedup vs baseline: 1.5391x; 1.0236x over previous
//
#include <hip/hip_runtime.h>

// RoiAlign (tf.image.crop_and_resize, bilinear, extrapolation=0)
// fm [8,64,64,256] f32, boxes [8,1000,4] f32, P=7 -> out [8,1000,7,7,256] f32.
//
// Mapping: 1 wave per 4 consecutive output positions; lane i -> channels
// [4i,4i+4) as float4 (64 lanes * 16B = 1KB coalesced per tap load / store).
// 4 positions/wave: 16 tap loads issued up front (4x MLP of the 1-pos
// version), endpgm store-drain amortized 4x.
//
// XCD-batch partitioning: b = blockIdx.x % 8 -> each XCD serves one batch;
// that batch's fm slice (4MB) == one XCD L2.
//
// Non-temporal output stores keep the 401MB write stream from evicting fm
// out of L2 (round-3: 134 -> 96.6 us).

#define BATCH 8
#define FH 64
#define FW 64
#define FC 256
#define NBOX 1000
#define PP 7
#define POS_PER_BATCH (NBOX * PP * PP)   // 49000
#define NPW 4                            // positions per wave

typedef __attribute__((ext_vector_type(4))) float f32x4;

__global__ __launch_bounds__(256, 4) void roi_align_kernel(
    const float* __restrict__ fm,
    const float* __restrict__ boxes,
    float* __restrict__ out)
{
    const int lane = threadIdx.x & 63;
    const int wib  = threadIdx.x >> 6;          // wave in block: 0..3

    const int b    = blockIdx.x & 7;            // batch == XCD (round-robin)
    const int lblk = blockIdx.x >> 3;
    const int base = lblk * (4 * NPW) + wib * NPW;   // first position of wave

    const int c4 = lane * 4;                    // channel offset for this lane
    const float* __restrict__ fmb = fm + (size_t)b * FH * FW * FC + c4;

    float4 v00[NPW], v01[NPW], v10[NPW], v11[NPW];
    float wxv[NPW], wyv[NPW], vmask[NPW];
    bool  vpos[NPW];

    // Phase 1: coords + issue all 16 tap loads (in flight together)
    #pragma unroll
    for (int i = 0; i < NPW; ++i) {
        const int p  = base + i;
        vpos[i] = (p < POS_PER_BATCH);
        const int pc = vpos[i] ? p : (POS_PER_BATCH - 1);   // clamp for safety

        const int pp = pc % (PP * PP);
        const int n  = pc / (PP * PP);
        const int py = pp / PP;
        const int px = pp % PP;

        const float* bx = boxes + (b * NBOX + n) * 4;
        const float y1 = bx[0];
        const float x1 = bx[1];
        const float y2 = bx[2];
        const float x2 = bx[3];

        // Reference: ys = y1*(h-1) + t*((y2-y1)*(h-1)/(P-1))  (exact order)
        const float yc = y1 * (float)(FH - 1)
                       + (float)py * ((y2 - y1) * (float)(FH - 1) / (float)(PP - 1));
        const float xc = x1 * (float)(FW - 1)
                       + (float)px * ((x2 - x1) * (float)(FW - 1) / (float)(PP - 1));

        const float ylo_f = floorf(yc);
        wyv[i] = yc - ylo_f;
        int y_lo = (int)ylo_f;
        int y_hi = y_lo + 1;
        y_lo = min(max(y_lo, 0), FH - 1);
        y_hi = min(max(y_hi, 0), FH - 1);
        const bool vy = (yc >= 0.0f) && (yc <= (float)(FH - 1));

        const float xlo_f = floorf(xc);
        wxv[i] = xc - xlo_f;
        int x_lo = (int)xlo_f;
        int x_hi = x_lo + 1;
        x_lo = min(max(x_lo, 0), FW - 1);
        x_hi = min(max(x_hi, 0), FW - 1);
        const bool vx = (xc >= 0.0f) && (xc <= (float)(FW - 1));

        vmask[i] = (vy && vx) ? 1.0f : 0.0f;

        // fm[b, y, x, c]: indices clamped -> always safe
        v00[i] = *(const float4*)(fmb + (size_t)(y_lo * FW + x_lo) * FC);
        v01[i] = *(const float4*)(fmb + (size_t)(y_lo * FW + x_hi) * FC);
        v10[i] = *(const float4*)(fmb + (size_t)(y_hi * FW + x_lo) * FC);
        v11[i] = *(const float4*)(fmb + (size_t)(y_hi * FW + x_hi) * FC);
    }

    // Phase 2: interpolate + NT store per position
    #pragma unroll
    for (int i = 0; i < NPW; ++i) {
        if (!vpos[i]) continue;
        const float wx = wxv[i], wy = wyv[i], vm = vmask[i];
        float4 top, bot;
        f32x4 r;
        top.x = v00[i].x + (v01[i].x - v00[i].x) * wx;
        top.y = v00[i].y + (v01[i].y - v00[i].y) * wx;
        top.z = v00[i].z + (v01[i].z - v00[i].z) * wx;
        top.w = v00[i].w + (v01[i].w - v00[i].w) * wx;
        bot.x = v10[i].x + (v11[i].x - v10[i].x) * wx;
        bot.y = v10[i].y + (v11[i].y - v10[i].y) * wx;
        bot.z = v10[i].z + (v11[i].z - v10[i].z) * wx;
        bot.w = v10[i].w + (v11[i].w - v10[i].w) * wx;
        r.x = (top.x + (bot.x - top.x) * wy) * vm;
        r.y = (top.y + (bot.y - top.y) * wy) * vm;
        r.z = (top.z + (bot.z - top.z) * wy) * vm;
        r.w = (top.w + (bot.w - top.w) * wy) * vm;

        float* po = out + ((size_t)b * POS_PER_BATCH + (base + i)) * FC + c4;
        __builtin_nontemporal_store(r, (f32x4*)po);
    }
}

extern "C" void kernel_launch(void* const* d_in, const int* in_sizes, int n_in,
                              void* d_out, int out_size, void* d_ws, size_t ws_size,
                              hipStream_t stream) {
    const float* fm    = (const float*)d_in[0];
    const float* boxes = (const float*)d_in[1];
    float* out = (float*)d_out;

    const int threads   = 256;                       // 4 waves/block
    const int pos_per_blk = 4 * NPW;                 // 16
    const int lblks     = (POS_PER_BATCH + pos_per_blk - 1) / pos_per_blk; // 3063
    const int blocks    = BATCH * lblks;             // 24504

    roi_align_kernel<<<blocks, threads, 0, stream>>>(fm, boxes, out);
}

// Round 5
// 81.778 us; speedup vs baseline: 1.7770x; 1.1546x over previous
//
#include <hip/hip_runtime.h>

// RoiAlign (tf.image.crop_and_resize, bilinear, extrapolation=0)
// fm [8,64,64,256] f32, boxes [8,1000,4] f32, P=7 -> out [8,1000,7,7,256] f32.
//
// Mapping: 1 wave per (box, py) row -> 7 positions (px=0..6). Lane i covers
// channels [4i,4i+4) as float4 (64 lanes * 16B = 1KB per tap load / store).
// Row mapping amortizes: box load + y-coordinate math once per 7 positions,
// 28 tap loads in one burst, 7KB contiguous NT store stream per wave.
//
// XCD-batch partitioning: b = blockIdx.x % 8 -> each XCD serves one batch;
// that batch's fm slice (4MB) == one XCD L2 (round-2: +8%).
// NT stores keep the 401MB write stream from evicting fm from L2
// (round-3: 134 -> 96.6 us).

#define BATCH 8
#define FH 64
#define FW 64
#define FC 256
#define NBOX 1000
#define PP 7
#define POS_PER_BATCH (NBOX * PP * PP)   // 49000
#define ROWS_PER_BATCH (NBOX * PP)       // 7000

typedef __attribute__((ext_vector_type(4))) float f32x4;

__global__ __launch_bounds__(256, 3) void roi_align_kernel(
    const float* __restrict__ fm,
    const float* __restrict__ boxes,
    float* __restrict__ out)
{
    const int lane = threadIdx.x & 63;
    const int wib  = threadIdx.x >> 6;          // wave in block: 0..3

    const int b    = blockIdx.x & 7;            // batch == XCD (round-robin)
    const int lblk = blockIdx.x >> 3;           // 0..1749
    const int row  = lblk * 4 + wib;            // 0..6999  (= n*7 + py)

    const int n  = row / PP;
    const int py = row % PP;

    const int c4 = lane * 4;                    // channel offset for this lane
    const float* __restrict__ fmb = fm + (size_t)b * FH * FW * FC + c4;

    // Box: [y1,x1,y2,x2] normalized (wave-uniform)
    const float* bx = boxes + (b * NBOX + n) * 4;
    const float y1 = bx[0];
    const float x1 = bx[1];
    const float y2 = bx[2];
    const float x2 = bx[3];

    // y: once per row. Reference: ys = y1*(h-1) + t*((y2-y1)*(h-1)/(P-1))
    const float yc = y1 * (float)(FH - 1)
                   + (float)py * ((y2 - y1) * (float)(FH - 1) / (float)(PP - 1));
    const float ylo_f = floorf(yc);
    const float wy    = yc - ylo_f;
    int y_lo = (int)ylo_f;
    int y_hi = y_lo + 1;
    y_lo = min(max(y_lo, 0), FH - 1);
    y_hi = min(max(y_hi, 0), FH - 1);
    const bool vy = (yc >= 0.0f) && (yc <= (float)(FH - 1));

    const float xstep = (x2 - x1) * (float)(FW - 1) / (float)(PP - 1);
    const float xbase = x1 * (float)(FW - 1);

    const float* rlo = fmb + (size_t)(y_lo * FW) * FC;
    const float* rhi = fmb + (size_t)(y_hi * FW) * FC;

    float wxv[PP], vmask[PP];
    float4 v00[PP], v01[PP], v10[PP], v11[PP];

    // Phase 1: x-coords + issue all 28 tap loads
    #pragma unroll
    for (int px = 0; px < PP; ++px) {
        const float xc = xbase + (float)px * xstep;   // exact reference order
        const float xlo_f = floorf(xc);
        wxv[px] = xc - xlo_f;
        int x_lo = (int)xlo_f;
        int x_hi = x_lo + 1;
        x_lo = min(max(x_lo, 0), FW - 1);
        x_hi = min(max(x_hi, 0), FW - 1);
        const bool vx = (xc >= 0.0f) && (xc <= (float)(FW - 1));
        vmask[px] = (vy && vx) ? 1.0f : 0.0f;

        v00[px] = *(const float4*)(rlo + (size_t)x_lo * FC);
        v01[px] = *(const float4*)(rlo + (size_t)x_hi * FC);
        v10[px] = *(const float4*)(rhi + (size_t)x_lo * FC);
        v11[px] = *(const float4*)(rhi + (size_t)x_hi * FC);
    }

    // Phase 2: interpolate + NT store (7 contiguous 1KB stores -> 7KB stream)
    float* po = out + ((size_t)b * POS_PER_BATCH + (size_t)row * PP) * FC + c4;
    #pragma unroll
    for (int px = 0; px < PP; ++px) {
        const float wx = wxv[px], vm = vmask[px];
        float4 top, bot;
        f32x4 r;
        top.x = v00[px].x + (v01[px].x - v00[px].x) * wx;
        top.y = v00[px].y + (v01[px].y - v00[px].y) * wx;
        top.z = v00[px].z + (v01[px].z - v00[px].z) * wx;
        top.w = v00[px].w + (v01[px].w - v00[px].w) * wx;
        bot.x = v10[px].x + (v11[px].x - v10[px].x) * wx;
        bot.y = v10[px].y + (v11[px].y - v10[px].y) * wx;
        bot.z = v10[px].z + (v11[px].z - v10[px].z) * wx;
        bot.w = v10[px].w + (v11[px].w - v10[px].w) * wx;
        r.x = (top.x + (bot.x - top.x) * wy) * vm;
        r.y = (top.y + (bot.y - top.y) * wy) * vm;
        r.z = (top.z + (bot.z - top.z) * wy) * vm;
        r.w = (top.w + (bot.w - top.w) * wy) * vm;

        __builtin_nontemporal_store(r, (f32x4*)(po + (size_t)px * FC));
    }
}

extern "C" void kernel_launch(void* const* d_in, const int* in_sizes, int n_in,
                              void* d_out, int out_size, void* d_ws, size_t ws_size,
                              hipStream_t stream) {
    const float* fm    = (const float*)d_in[0];
    const float* boxes = (const float*)d_in[1];
    float* out = (float*)d_out;

    const int threads = 256;                              // 4 waves/block
    const int blocks  = BATCH * (ROWS_PER_BATCH / 4);     // 8 * 1750 = 14000

    roi_align_kernel<<<blocks, threads, 0, stream>>>(fm, boxes, out);
}